// Round 2
// baseline (288.945 us; speedup 1.0000x reference)
//
#include <hip/hip_runtime.h>

#define NF    25     // input features per row
#define NPAIR 300    // upper-triangle pairs (25*24/2)
#define NCOL  425    // output cols: 25*5 + 300
#define ROWS  8      // rows staged per block-chunk
#define BLK   256

__global__ __launch_bounds__(BLK) void feat_expand_kernel(
    const float* __restrict__ x, float* __restrict__ out,
    int nrows, int nchunks) {
  __shared__ float  xs[ROWS * NF];      // 800 B
  __shared__ unsigned short pairs[NPAIR];

  const int tid = threadIdx.x;

  // Build (i,j) pair table once per block: pair p -> (i, j), i<j, row-major.
  // NPAIR (300) > BLK (256): must stride, not just mask!
  for (int p = tid; p < NPAIR; p += BLK) {
    int rem = p, i = 0;
    while (rem >= (NF - 1 - i)) { rem -= (NF - 1 - i); ++i; }
    const int j = i + 1 + rem;
    pairs[p] = (unsigned short)(i | (j << 8));
  }

  for (int chunk = blockIdx.x; chunk < nchunks; chunk += gridDim.x) {
    const long long rowbase = (long long)chunk * ROWS;

    __syncthreads();  // xs safe to overwrite; also fences pairs on first iter

    // Stage ROWS*NF = 200 input floats, coalesced
    if (tid < ROWS * NF) {
      const long long g = rowbase * NF + tid;
      if (g < (long long)nrows * NF) xs[tid] = x[g];
    }
    __syncthreads();

    // Write ROWS*NCOL = 3400 output elements, flat & coalesced
    const long long obase = rowbase * NCOL;
    const int total = ROWS * NCOL;
    for (int o = tid; o < total; o += BLK) {
      const int r = o / NCOL;          // constant divisor -> magic multiply
      if (rowbase + r >= nrows) break; // o ascending => r ascending
      const int c = o - r * NCOL;
      const float* __restrict__ xr = &xs[r * NF];

      float v;
      if (c < 125) {
        if (c < 25) {
          v = xr[c];
        } else if (c < 50) {
          const float t = xr[c - 25];
          v = t * t;
        } else {
          // log / sqrt / cbrt of |x| + eps
          int idx = (c < 75) ? (c - 50) : ((c < 100) ? (c - 75) : (c - 100));
          const float t = fabsf(xr[idx]) + 1e-10f;
          if (c < 75)       v = logf(t);
          else if (c < 100) v = sqrtf(t);
          else              v = cbrtf(t);
        }
      } else {
        const unsigned short pr = pairs[c - 125];
        v = xr[pr & 0xFF] * xr[pr >> 8];
      }
      out[obase + o] = v;
    }
  }
}

extern "C" void kernel_launch(void* const* d_in, const int* in_sizes, int n_in,
                              void* d_out, int out_size, void* d_ws, size_t ws_size,
                              hipStream_t stream) {
  const float* x = (const float*)d_in[0];
  float* out = (float*)d_out;

  const int nrows = in_sizes[0] / NF;                 // 524288
  const int nchunks = (nrows + ROWS - 1) / ROWS;      // 65536
  const int grid = nchunks < 4096 ? nchunks : 4096;

  feat_expand_kernel<<<grid, BLK, 0, stream>>>(x, out, nrows, nchunks);
}

// Round 4
// 212.599 us; speedup vs baseline: 1.3591x; 1.3591x over previous
//
#include <hip/hip_runtime.h>

#define NF    25     // input features per row
#define NPAIR 300    // upper-triangle pairs (25*24/2)
#define NCOL  425    // output cols: 25*5 + 300
#define ROWS  8      // rows staged per block-chunk
#define BLK   256
#define TILE4 (ROWS * NCOL / 4)   // 850 float4s per chunk (13600 B, 16B-aligned)

typedef float f32x4 __attribute__((ext_vector_type(4)));

__global__ __launch_bounds__(BLK) void feat_expand_kernel(
    const float* __restrict__ x, float* __restrict__ out,
    int nrows, int nchunks) {
  __shared__ f32x4 tile4[TILE4];            // 13600 B, 16B-aligned
  __shared__ float  xs[ROWS * NF];          // 800 B
  __shared__ unsigned short pairs[NPAIR];   // 600 B
  float* tile = (float*)tile4;

  const int tid = threadIdx.x;

  // (i,j) pair table, row-major upper triangle. NPAIR > BLK: stride it.
  for (int p = tid; p < NPAIR; p += BLK) {
    int rem = p, i = 0;
    while (rem >= (NF - 1 - i)) { rem -= (NF - 1 - i); ++i; }
    pairs[p] = (unsigned short)(i | ((i + 1 + rem) << 8));
  }

  for (int chunk = blockIdx.x; chunk < nchunks; chunk += gridDim.x) {
    const long long rowbase = (long long)chunk * ROWS;
    const int rows_here = (int)((nrows - rowbase) < ROWS ? (nrows - rowbase) : ROWS);

    __syncthreads();  // protect xs/tile from previous iteration's readers

    // Phase A: stage 200 input floats, coalesced
    if (tid < ROWS * NF) {
      const int r = tid / NF;
      if (r < rows_here) xs[tid] = x[rowbase * NF + tid];
    }
    __syncthreads();

    // Phase B1: unary features — one thread per (row, input col), branch-free.
    if (tid < ROWS * NF) {
      const int r = tid / NF, i = tid - r * NF;
      if (r < rows_here) {
        float* tr = &tile[r * NCOL];
        const float v  = xs[tid];
        const float ax = fabsf(v) + 1e-10f;
        const float l2 = __builtin_amdgcn_logf(ax);      // v_log_f32: log2(ax)
        tr[i]          = v;                              // identity
        tr[NF + i]     = v * v;                          // square
        tr[2*NF + i]   = l2 * 0.69314718055994530942f;   // ln = log2*ln2
        tr[3*NF + i]   = sqrtf(ax);                      // v_sqrt_f32
        tr[4*NF + i]   = __builtin_amdgcn_exp2f(l2 * (1.0f/3.0f)); // cbrt
      }
    }
    // Phase B2: pairwise products, flat strided, branch-free
    for (int p = tid; p < ROWS * NPAIR; p += BLK) {
      const int r = p / NPAIR, q = p - r * NPAIR;
      if (r < rows_here) {
        const unsigned short pr = pairs[q];
        tile[r * NCOL + 5*NF + q] =
            xs[r * NF + (pr & 0xFF)] * xs[r * NF + (pr >> 8)];
      }
    }
    __syncthreads();

    // Phase C: copy tile -> global as aligned float4 streaming stores
    if (rows_here == ROWS) {
      f32x4* __restrict__ o4 = (f32x4*)(out + rowbase * NCOL);
      for (int v = tid; v < TILE4; v += BLK)
        __builtin_nontemporal_store(tile4[v], &o4[v]);
    } else {  // tail chunk (not hit at 524288 rows, kept for correctness)
      const int total = rows_here * NCOL;
      for (int o = tid; o < total; o += BLK)
        out[rowbase * NCOL + o] = tile[o];
    }
  }
}

extern "C" void kernel_launch(void* const* d_in, const int* in_sizes, int n_in,
                              void* d_out, int out_size, void* d_ws, size_t ws_size,
                              hipStream_t stream) {
  const float* x = (const float*)d_in[0];
  float* out = (float*)d_out;

  const int nrows = in_sizes[0] / NF;                 // 524288
  const int nchunks = (nrows + ROWS - 1) / ROWS;      // 65536
  const int grid = nchunks < 4096 ? nchunks : 4096;

  feat_expand_kernel<<<grid, BLK, 0, stream>>>(x, out, nrows, nchunks);
}